// Round 3
// baseline (1993.795 us; speedup 1.0000x reference)
//
#include <hip/hip_runtime.h>

#define B_ 8
#define N_ 8192
#define S_ 1024
#define NS_ 64

// out layout (floats) — also used as staging (fully rewritten every launch)
#define OUT0 0                 // new_xyz (B,3,1024)
#define OUT1 24576             // new_points (B,128,1024); rows 0..63 of each
                               //   column hold gi int-bits between kernels 3&4
#define OUT2 1073152           // new_seed (B,1024); holds fps int-bits between
                               //   kernels 1&2

// ---------------------------------------------------------------------------
// Kernel 1: farthest point sampling. One block per batch, sequential 1024
// steps. Reference f32 op order (contract off) so argmax decisions match
// numpy exactly; ties broken to lowest index via LDS atomicMin. Result
// indices stored as int-bits in the OUT2 region.
// ---------------------------------------------------------------------------
__global__ __launch_bounds__(512) void fps_kernel(const float* __restrict__ xyz,
                                                  float* out) {
    const int b = blockIdx.x;
    const int t = threadIdx.x;
    const int lane = t & 63;
    const int wid = t >> 6;
    const float* X = xyz + b * 3 * N_;

    float px[16], py[16], pz[16], dist[16];
#pragma unroll
    for (int j = 0; j < 16; ++j) {
        int n = t + 512 * j;
        px[j] = X[n];
        py[j] = X[N_ + n];
        pz[j] = X[2 * N_ + n];
        dist[j] = 1e10f;
    }

    __shared__ float cx, cy, cz;
    __shared__ float pv[8];
    __shared__ float gmax_s;
    __shared__ int far_s;
    if (t == 0) far_s = 0;
    __syncthreads();

    float* oseed = out + OUT2 + b * S_;

    for (int step = 0; step < S_; ++step) {
        // phase A: everyone reads centroid index; owner pushes coords to LDS
        int ci = far_s & 8191;              // clamp: fault -> wrong answer
        if (t == (ci & 511)) {
            int j = (ci >> 9) & 15;
            cx = px[j]; cy = py[j]; cz = pz[j];
        }
        if (t == 0) oseed[step] = __int_as_float(ci);
        __syncthreads();   // B1

        float c0 = cx, c1 = cy, c2 = cz;
        if (t == 0) far_s = 0x7fffffff;     // reset for this round's atomicMin

        // phase B: dist update (reference op order) + value-only max
        float m = -1.0f;
        {
#pragma clang fp contract(off)
#pragma unroll
            for (int j = 0; j < 16; ++j) {
                float e0 = px[j] - c0;
                float e1 = py[j] - c1;
                float e2 = pz[j] - c2;
                float d = (e0 * e0 + e1 * e1) + e2 * e2;
                float dm = fminf(dist[j], d);
                dist[j] = dm;
                m = fmaxf(m, dm);
            }
        }
#pragma unroll
        for (int off = 32; off > 0; off >>= 1)
            m = fmaxf(m, __shfl_down(m, off, 64));
        if (lane == 0) pv[wid] = m;
        __syncthreads();   // B2

        if (t == 0) {
            float g = pv[0];
#pragma unroll
            for (int w = 1; w < 8; ++w) g = fmaxf(g, pv[w]);
            gmax_s = g;
        }
        __syncthreads();   // B3

        // phase D: owners of the max value race to the lowest index
        float g = gmax_s;
        int nc = 0x7fffffff;
#pragma unroll
        for (int j = 0; j < 16; ++j) {
            if (dist[j] == g) nc = min(nc, t + 512 * j);
        }
        if (nc != 0x7fffffff) atomicMin(&far_s, nc);
        __syncthreads();   // B4
    }
}

// ---------------------------------------------------------------------------
// Kernel 2: read fps int-bits from OUT2, gather centroid coords -> OUT0,
// overwrite OUT2 with the gathered seed value (same-thread read-then-write).
// ---------------------------------------------------------------------------
__global__ __launch_bounds__(256) void gather_kernel(const float* __restrict__ xyz,
                                                     const int* __restrict__ seed,
                                                     float* out) {
    int t = blockIdx.x * 256 + threadIdx.x;   // 8192
    int b = t >> 10, s = t & 1023;
    int idx = __float_as_int(out[OUT2 + t]) & 8191;
    const float* X = xyz + b * 3 * N_;
    float x = X[idx], y = X[N_ + idx], z = X[2 * N_ + idx];
    out[OUT0 + (b * 3 + 0) * S_ + s] = x;
    out[OUT0 + (b * 3 + 1) * S_ + s] = y;
    out[OUT0 + (b * 3 + 2) * S_ + s] = z;
    out[OUT2 + t] = (float)seed[b * N_ + idx];
}

// ---------------------------------------------------------------------------
// Kernel 3: ball query. One wave per centroid; ballot-compaction collects the
// 64 lowest-index in-radius points; pad with first. |c|^2 and |x|^2
// recomputed inline in the reference op order; result indices stored as
// int-bits in rows 0..63 of this centroid's own OUT1 column.
// ---------------------------------------------------------------------------
__global__ __launch_bounds__(256) void ballquery_kernel(const float* __restrict__ xyz,
                                                        float* out) {
    int wid = threadIdx.x >> 6, lane = threadIdx.x & 63;
    int sg = blockIdx.x * 4 + wid;            // 0..8191 centroid id
    int b = sg >> 10, s = sg & 1023;
    const float* X = xyz + b * 3 * N_;
    float c0 = out[OUT0 + (b * 3 + 0) * S_ + s];
    float c1 = out[OUT0 + (b * 3 + 1) * S_ + s];
    float c2 = out[OUT0 + (b * 3 + 2) * S_ + s];
    float ss;
    {
#pragma clang fp contract(off)
        ss = (c0 * c0 + c1 * c1) + c2 * c2;
    }
    float* G = out + OUT1 + (b * 128) * S_ + s;   // column s, rows 0..63, stride S_

    int cnt = 0, first = 0;
    for (int base = 0; base < N_ && cnt < NS_; base += 64) {
        int n = base + lane;
        float x = X[n], y = X[N_ + n], z = X[2 * N_ + n];
        float d;
        {
#pragma clang fp contract(off)
            float ds = (x * x + y * y) + z * z;
            float dot = (x * c0 + y * c1) + z * c2;
            d = ((-2.0f * dot) + ss) + ds;
        }
        bool inr = (d <= 0.04f);
        unsigned long long mask = __ballot(inr);
        if (mask) {
            if (cnt == 0) first = base + __ffsll((unsigned long long)mask) - 1;
            int pos = cnt + (int)__popcll(mask & ((1ull << lane) - 1ull));
            if (inr && pos < NS_) G[pos * S_] = __int_as_float(n);
            cnt += (int)__popcll(mask);
        }
    }
    if (lane >= cnt && lane < NS_) G[lane * S_] = __int_as_float(first);
}

// ---------------------------------------------------------------------------
// Kernel 4: fused gather + 3-layer pointwise MLP (+BN+ReLU) + max over K.
// One block (256 thr) per centroid. k = lane (64 rows), wave wq owns an
// o-slice. Reads gi int-bits from its own OUT1 column, then overwrites that
// column with the final features (read happens before first barrier; writes
// at the end — same block only, race-free).
// ---------------------------------------------------------------------------
__global__ __launch_bounds__(256) void mlp_kernel(
    const float* __restrict__ xyz, const float* __restrict__ pts,
    const float* __restrict__ w0, const float* __restrict__ b0,
    const float* __restrict__ g0, const float* __restrict__ be0,
    const float* __restrict__ m0, const float* __restrict__ v0,
    const float* __restrict__ w1, const float* __restrict__ b1,
    const float* __restrict__ g1, const float* __restrict__ be1,
    const float* __restrict__ m1, const float* __restrict__ v1,
    const float* __restrict__ w2, const float* __restrict__ b2,
    const float* __restrict__ g2, const float* __restrict__ be2,
    const float* __restrict__ m2, const float* __restrict__ v2,
    float* out) {
    const int sg = blockIdx.x;
    const int b = sg >> 10, s = sg & 1023;
    const int t = threadIdx.x;
    const int lane = t & 63;
    const int wq = __builtin_amdgcn_readfirstlane(t >> 6);

    __shared__ float f0[64 * 9];
    __shared__ float bufA[64 * 65];
    __shared__ float bufB[64 * 65];

    if (t < 64) {
        int gidx = __float_as_int(out[OUT1 + (b * 128 + t) * S_ + s]) & 8191;
        const float* X = xyz + b * 3 * N_;
        const float* P = pts + b * 3 * N_;
        float cx = out[OUT0 + (b * 3 + 0) * S_ + s];
        float cy = out[OUT0 + (b * 3 + 1) * S_ + s];
        float cz = out[OUT0 + (b * 3 + 2) * S_ + s];
        f0[t * 9 + 0] = X[gidx] - cx;
        f0[t * 9 + 1] = X[N_ + gidx] - cy;
        f0[t * 9 + 2] = X[2 * N_ + gidx] - cz;
        f0[t * 9 + 3] = P[gidx];
        f0[t * 9 + 4] = P[N_ + gidx];
        f0[t * 9 + 5] = P[2 * N_ + gidx];
    }
    __syncthreads();

    // layer 0: 6 -> 64
    {
        float in[6];
#pragma unroll
        for (int c = 0; c < 6; ++c) in[c] = f0[lane * 9 + c];
#pragma unroll 1
        for (int i = 0; i < 16; ++i) {
            int o = wq * 16 + i;
            float acc = 0.0f;
#pragma unroll
            for (int c = 0; c < 6; ++c) acc = fmaf(in[c], w0[o * 6 + c], acc);
            float sc = g0[o] / sqrtf(v0[o] + 1e-5f);
            float y = (acc + b0[o] - m0[o]) * sc + be0[o];
            bufA[lane * 65 + o] = fmaxf(y, 0.0f);
        }
    }
    __syncthreads();

    // layer 1: 64 -> 64
    {
        float r[64];
#pragma unroll
        for (int c = 0; c < 64; ++c) r[c] = bufA[lane * 65 + c];
#pragma unroll 1
        for (int i = 0; i < 16; ++i) {
            int o = wq * 16 + i;
            float acc = 0.0f;
#pragma unroll
            for (int c = 0; c < 64; ++c) acc = fmaf(r[c], w1[o * 64 + c], acc);
            float sc = g1[o] / sqrtf(v1[o] + 1e-5f);
            float y = (acc + b1[o] - m1[o]) * sc + be1[o];
            bufB[lane * 65 + o] = fmaxf(y, 0.0f);
        }
    }
    __syncthreads();

    // layer 2: 64 -> 128, fused BN+ReLU+max over k (k = lane -> wave reduce)
    {
        float r[64];
#pragma unroll
        for (int c = 0; c < 64; ++c) r[c] = bufB[lane * 65 + c];
#pragma unroll 1
        for (int i = 0; i < 32; ++i) {
            int o = wq * 32 + i;
            float acc = 0.0f;
#pragma unroll
            for (int c = 0; c < 64; ++c) acc = fmaf(r[c], w2[o * 64 + c], acc);
            float sc = g2[o] / sqrtf(v2[o] + 1e-5f);
            float y = (acc + b2[o] - m2[o]) * sc + be2[o];
            y = fmaxf(y, 0.0f);
#pragma unroll
            for (int off = 1; off < 64; off <<= 1)
                y = fmaxf(y, __shfl_xor(y, off, 64));
            if (lane == 0) out[OUT1 + (b * 128 + o) * S_ + s] = y;
        }
    }
}

extern "C" void kernel_launch(void* const* d_in, const int* in_sizes, int n_in,
                              void* d_out, int out_size, void* d_ws, size_t ws_size,
                              hipStream_t stream) {
    const float* xyz  = (const float*)d_in[0];
    const float* pts  = (const float*)d_in[1];
    const int*   seed = (const int*)d_in[2];
    const float* w0 = (const float*)d_in[3];
    const float* b0 = (const float*)d_in[4];
    const float* g0 = (const float*)d_in[5];
    const float* be0 = (const float*)d_in[6];
    const float* m0 = (const float*)d_in[7];
    const float* v0 = (const float*)d_in[8];
    const float* w1 = (const float*)d_in[9];
    const float* b1 = (const float*)d_in[10];
    const float* g1 = (const float*)d_in[11];
    const float* be1 = (const float*)d_in[12];
    const float* m1 = (const float*)d_in[13];
    const float* v1 = (const float*)d_in[14];
    const float* w2 = (const float*)d_in[15];
    const float* b2 = (const float*)d_in[16];
    const float* g2 = (const float*)d_in[17];
    const float* be2 = (const float*)d_in[18];
    const float* m2 = (const float*)d_in[19];
    const float* v2 = (const float*)d_in[20];
    float* out = (float*)d_out;
    (void)d_ws; (void)ws_size;   // workspace intentionally unused

    fps_kernel<<<dim3(B_), dim3(512), 0, stream>>>(xyz, out);
    gather_kernel<<<dim3(8192 / 256), dim3(256), 0, stream>>>(xyz, seed, out);
    ballquery_kernel<<<dim3(2048), dim3(256), 0, stream>>>(xyz, out);
    mlp_kernel<<<dim3(8192), dim3(256), 0, stream>>>(xyz, pts,
        w0, b0, g0, be0, m0, v0,
        w1, b1, g1, be1, m1, v1,
        w2, b2, g2, be2, m2, v2,
        out);
}